// Round 5
// baseline (493.822 us; speedup 1.0000x reference)
//
#include <hip/hip_runtime.h>

typedef unsigned int u32;
typedef __bf16 bf16x8 __attribute__((ext_vector_type(8)));
typedef float f32x4 __attribute__((ext_vector_type(4)));

#define Tn 4
#define Bn 32
#define Cn 384
#define Nn 196
#define Hn 12
#define CNn (Cn*Nn)         // 75264
#define BCNn (Bn*CNn)       // 2408448
#define BHNn (Bn*Hn*Nn)     // 75264
#define PBITS (Tn*BHNn)     // 301056
#define TBCNn (Tn*BCNn)     // 9633792
#define NCOLS 6272          // B*N
#define WSZ 147456          // 384*384

// fp32 -> 3-way bf16 split (exact residuals in fp32; h+m+l = x to ~2^-25)
__device__ __forceinline__ void split3(float v, __bf16& h, __bf16& m, __bf16& l) {
  h = (__bf16)v;  float r = v - (float)h;
  m = (__bf16)r;  float r2 = r - (float)m;
  l = (__bf16)r2;
}

// ---------------------------------------------------------------------------
// W [4][384][384] fp32, scaled by BN iv -> wsp [4][3][384][384] bf16, plus
// shv[p][o] = BN shift (+ bias*iv folded for proj).
// ---------------------------------------------------------------------------
struct WSplitArgs {
  const float* w[4]; const float* g[4]; const float* be[4];
  const float* mu[4]; const float* va[4]; const float* bias;
};
__global__ __launch_bounds__(256) void split_w(
    WSplitArgs a, __bf16* __restrict__ wsp, float* __restrict__ shv) {
  const int i = blockIdx.x * 256 + threadIdx.x;   // < 589824
  const int p = i / WSZ, r = i - p * WSZ;
  const int o = r / Cn;
  const float iv = a.g[p][o] / sqrtf(a.va[p][o] + 1e-5f);
  __bf16 h, m, l;
  split3(a.w[p][r] * iv, h, m, l);
  wsp[(size_t)(p * 3 + 0) * WSZ + r] = h;
  wsp[(size_t)(p * 3 + 1) * WSZ + r] = m;
  wsp[(size_t)(p * 3 + 2) * WSZ + r] = l;
  if (r - o * Cn == 0) {
    float sh = a.be[p][o] - a.mu[p][o] * iv;
    if (p == 3) sh += a.bias[o] * iv;
    shv[p * Cn + o] = sh;
  }
}

// x [t,b,c,n] fp32 -> xT [t][col=(b,n)][c] fp32
__global__ __launch_bounds__(256) void transpose_x(
    const float* __restrict__ x, float* __restrict__ xT) {
  const int t = blockIdx.x, b = blockIdx.y, ch = blockIdx.z;
  const int n = threadIdx.x;
  if (n >= Nn) return;
  const float* xp = x + (size_t)t * BCNn + (size_t)b * CNn + n;
  float* op = xT + ((size_t)t * NCOLS + (size_t)b * Nn + n) * Cn;
  const int c0 = ch * 192;
  for (int c = c0; c < c0 + 192; c += 4) {
    f32x4 v;
#pragma unroll
    for (int j = 0; j < 4; ++j) v[j] = xp[(size_t)(c + j) * Nn];
    *(f32x4*)(op + c) = v;
  }
}

// ---------------------------------------------------------------------------
// Fused QKV GEMM + LIF(th=1) + bitpack. Block = 128 o x 128 col, t-loop
// inside (LIF state in regs), 6-product split-bf16 MFMA. Grid 448 (441
// useful); the 9 (p,mt) variants of a col-group are contiguous on one XCD.
// Output: ONLY packed spike bits (no yT traffic).
// ---------------------------------------------------------------------------
struct BitsOut { u32* b[3]; };

__global__ __launch_bounds__(256, 2) void gemm_qkv_pack(
    const float* __restrict__ xT,    // [t][col][c] fp32
    const __bf16* __restrict__ wsp,  // [4][3][o][c] (iv-scaled)
    const float* __restrict__ shv,   // [4][o]
    BitsOut BO)
{
  __shared__ __bf16 Asw[3][128][32];
  __shared__ __bf16 Bsw[3][128][32];
  __shared__ u32 spk[128][33];       // [col][o-word] spike bytes, padded
  const int bid = blockIdx.x;
  const int xcd = bid & 7, slot = bid >> 3;       // slot 0..55
  const int l = xcd * 56 + slot;
  if (l >= 441) return;
  const int group = l / 9, v = l - group * 9;     // group = col tile
  const int col0 = group * 128;
  const int p = v / 3, mt = v - p * 3;
  const int o0 = mt * 128;
  const int tid = threadIdx.x, lane = tid & 63, wid = tid >> 6;
  const int wm = wid >> 1, wn = wid & 1;
  const int quad = lane >> 4, nl = lane & 15;
  const __bf16* Ag = wsp + (size_t)(p * 3) * WSZ;
  u32* bits = BO.b[p];

  // BN shift constants (per-lane rows), const across t
  f32x4 sh4[4];
#pragma unroll
  for (int mi = 0; mi < 4; ++mi)
    sh4[mi] = *(const f32x4*)&shv[p * Cn + o0 + wm * 64 + mi * 16 + quad * 4];

  f32x4 vst[4][4] = {};   // LIF state across t

  bf16x8 aval[6];
  f32x4 bval[2][2];
  {  // prefetch (t=0, kk=0)
    const float* Bg = xT + (size_t)col0 * Cn;
#pragma unroll
    for (int i = 0; i < 6; ++i) {
      const int u = tid + i * 256, s = u >> 9, rem = u & 511;
      const int row = rem >> 2, kb = rem & 3;
      aval[i] = *(const bf16x8*)(Ag + (size_t)s * WSZ + (size_t)(o0 + row) * Cn + kb * 8);
    }
#pragma unroll
    for (int i = 0; i < 2; ++i) {
      const int u = tid + i * 256, row = u >> 2, kb = u & 3;
      const float* src = Bg + (size_t)row * Cn + kb * 8;
      bval[i][0] = *(const f32x4*)src; bval[i][1] = *(const f32x4*)(src + 4);
    }
  }

  for (int t = 0; t < Tn; ++t) {
    f32x4 acc[4][4] = {};
    for (int kk = 0; kk < 12; ++kk) {
      __syncthreads();   // prev frag reads (or prev pack reads) done
#pragma unroll
      for (int i = 0; i < 6; ++i) {
        const int u = tid + i * 256, s = u >> 9, rem = u & 511;
        const int row = rem >> 2, kb = rem & 3;
        const int kbp = kb ^ ((row >> 1) & 3);
        *(bf16x8*)&Asw[s][row][kbp * 8] = aval[i];
      }
#pragma unroll
      for (int i = 0; i < 2; ++i) {
        const int u = tid + i * 256, row = u >> 2, kb = u & 3;
        const int kbp = kb ^ ((row >> 1) & 3);
        __bf16 h8[8], m8[8], l8[8];
#pragma unroll
        for (int j = 0; j < 8; ++j) {
          const float xv = (j < 4) ? bval[i][0][j] : bval[i][1][j - 4];
          split3(xv, h8[j], m8[j], l8[j]);
        }
        *(bf16x8*)&Bsw[0][row][kbp * 8] = *(bf16x8*)h8;
        *(bf16x8*)&Bsw[1][row][kbp * 8] = *(bf16x8*)m8;
        *(bf16x8*)&Bsw[2][row][kbp * 8] = *(bf16x8*)l8;
      }
      __syncthreads();
      // prefetch NEXT slab before MFMA -> latency hides behind matrix pipe
      const bool last = (kk == 11);
      const int nt = last ? t + 1 : t;
      const int nk = last ? 0 : kk + 1;
      if (nt < Tn) {
        const int k0n = nk * 32;
        const float* Bg = xT + ((size_t)nt * NCOLS + col0) * Cn;
#pragma unroll
        for (int i = 0; i < 6; ++i) {
          const int u = tid + i * 256, s = u >> 9, rem = u & 511;
          const int row = rem >> 2, kb = rem & 3;
          aval[i] = *(const bf16x8*)(Ag + (size_t)s * WSZ +
                                     (size_t)(o0 + row) * Cn + k0n + kb * 8);
        }
#pragma unroll
        for (int i = 0; i < 2; ++i) {
          const int u = tid + i * 256, row = u >> 2, kb = u & 3;
          const float* src = Bg + (size_t)row * Cn + k0n + kb * 8;
          bval[i][0] = *(const f32x4*)src; bval[i][1] = *(const f32x4*)(src + 4);
        }
      }
      bf16x8 af[3][4], bfr[3][4];
#pragma unroll
      for (int i = 0; i < 4; ++i) {
        const int ra = wm * 64 + i * 16 + nl;
        const int rb = wn * 64 + i * 16 + nl;
        const int ka = (quad ^ ((ra >> 1) & 3)) * 8;
        const int kb2 = (quad ^ ((rb >> 1) & 3)) * 8;
#pragma unroll
        for (int s = 0; s < 3; ++s) {
          af[s][i]  = *(const bf16x8*)&Asw[s][ra][ka];
          bfr[s][i] = *(const bf16x8*)&Bsw[s][rb][kb2];
        }
      }
#pragma unroll
      for (int mi = 0; mi < 4; ++mi)
#pragma unroll
        for (int ni = 0; ni < 4; ++ni) {
          f32x4 c = acc[mi][ni];
          c = __builtin_amdgcn_mfma_f32_16x16x32_bf16(af[0][mi], bfr[0][ni], c, 0, 0, 0);
          c = __builtin_amdgcn_mfma_f32_16x16x32_bf16(af[0][mi], bfr[1][ni], c, 0, 0, 0);
          c = __builtin_amdgcn_mfma_f32_16x16x32_bf16(af[1][mi], bfr[0][ni], c, 0, 0, 0);
          c = __builtin_amdgcn_mfma_f32_16x16x32_bf16(af[1][mi], bfr[1][ni], c, 0, 0, 0);
          c = __builtin_amdgcn_mfma_f32_16x16x32_bf16(af[0][mi], bfr[2][ni], c, 0, 0, 0);
          c = __builtin_amdgcn_mfma_f32_16x16x32_bf16(af[2][mi], bfr[0][ni], c, 0, 0, 0);
          acc[mi][ni] = c;
        }
    }
    // epilogue t: BN shift + LIF + spike bytes -> spk (per-wave disjoint)
#pragma unroll
    for (int mi = 0; mi < 4; ++mi)
#pragma unroll
      for (int ni = 0; ni < 4; ++ni) {
        u32 pk = 0;
#pragma unroll
        for (int r = 0; r < 4; ++r) {
          const float z = acc[mi][ni][r] + sh4[mi][r];
          const float nv = vst[mi][ni][r] + (z - vst[mi][ni][r]) * 0.5f;
          const bool s = nv >= 1.0f;
          pk |= (s ? 1u : 0u) << (r * 8);
          vst[mi][ni][r] = s ? 0.f : nv;
        }
        spk[wn * 64 + ni * 16 + nl][wm * 16 + mi * 4 + quad] = pk;
      }
    __syncthreads();
    // pack 512 (col, head) u32 masks; nibble gather via multiply trick
#pragma unroll
    for (int i = 0; i < 2; ++i) {
      const int u = tid + i * 256;
      const int cl = u & 127, head = u >> 7;   // head 0..3
      u32 m = 0;
#pragma unroll
      for (int j = 0; j < 8; ++j) {
        const u32 w = spk[cl][head * 8 + j];
        m |= ((((w & 0x01010101u) * 0x01020408u) >> 24) & 0xFu) << (j * 4);
      }
      const int col = col0 + cl;
      const int b = col / Nn, n = col - b * Nn;
      bits[(size_t)t * BHNn + ((size_t)b * Hn + (mt * 4 + head)) * Nn + n] = m;
    }
    // next t's kk=0 first sync orders pack-reads before LDS staging writes
  }
}

// ---------------------------------------------------------------------------
// Attention fused with LIF(0.5): one block per (b,h), t-loop inside, LIF
// state in regs, emits bf16 spikes -> sp[t][col][c].
// ---------------------------------------------------------------------------
__global__ __launch_bounds__(256) void attn_lif(
    const u32* __restrict__ qb, const u32* __restrict__ kb,
    const u32* __restrict__ vb, const float* __restrict__ policy,
    __bf16* __restrict__ sp) {
  __shared__ u32 qs[Nn], ks[Nn], vs[Nn];
  __shared__ float ps[Nn];
  __shared__ float vf[Nn * 32];
  const int b = blockIdx.x / Hn, h = blockIdx.x - b * Hn;
  const int tid = threadIdx.x;
  float v05[32];
#pragma unroll
  for (int d = 0; d < 32; ++d) v05[d] = 0.f;

  for (int t = 0; t < Tn; ++t) {
    const size_t boff = (size_t)t * BHNn + ((size_t)b * Hn + h) * Nn;
    for (int i = tid; i < Nn; i += 256) {
      qs[i] = qb[boff + i];
      ks[i] = kb[boff + i];
      vs[i] = vb[boff + i];
      ps[i] = policy[(size_t)(t * Bn + b) * Nn + i];
    }
    __syncthreads();
    for (int i = tid; i < Nn * 32; i += 256)
      vf[i] = (float)((vs[i >> 5] >> (i & 31)) & 1u);
    __syncthreads();
    if (tid < Nn) {
      const int n = tid;
      const u32 qn = qs[n];
      float acc[32];
#pragma unroll
      for (int d = 0; d < 32; ++d) acc[d] = 0.f;
      for (int m = 0; m < Nn; ++m) {
        const u32 a = __popc(qn & ks[m]);
        if (a) {  // skipped terms are exact zeros
          const float pm = ps[m];
          const float mask = (m == n) ? (pm + (1.0f - pm)) : pm;
          const float w = (float)a * mask;
          const float4* vr = (const float4*)(vf + m * 32);
#pragma unroll
          for (int q = 0; q < 8; ++q) {
            const float4 vv = vr[q];
            acc[q * 4 + 0] += w * vv.x; acc[q * 4 + 1] += w * vv.y;
            acc[q * 4 + 2] += w * vv.z; acc[q * 4 + 3] += w * vv.w;
          }
        }
      }
      __bf16* op = sp + (size_t)t * BCNn + ((size_t)b * Nn + n) * Cn + h * 32;
#pragma unroll
      for (int q = 0; q < 4; ++q) {
        __bf16 s8[8];
#pragma unroll
        for (int r = 0; r < 8; ++r) {
          const int d = q * 8 + r;
          const float y = acc[d] * 0.25f;
          const float nv = v05[d] + (y - v05[d]) * 0.5f;
          const bool s = nv >= 0.5f;
          s8[r] = (__bf16)(s ? 1.0f : 0.0f);
          v05[d] = s ? 0.f : nv;
        }
        *(bf16x8*)(op + q * 8) = *(bf16x8*)s8;
      }
    }
    __syncthreads();
  }
}

// ---------------------------------------------------------------------------
// proj GEMM: 3-split iv-scaled W x binary bf16 spikes -> z[t][col][o] (f32x4
// stores). XCD-swizzled (600 blocks), prefetch-before-MFMA pipeline.
// ---------------------------------------------------------------------------
__global__ __launch_bounds__(256, 2) void gemm_proj_mfma(
    const __bf16* __restrict__ sp, const __bf16* __restrict__ wsp,
    const float* __restrict__ shv, float* __restrict__ z)
{
  __shared__ __bf16 Asw[3][128][32];
  __shared__ __bf16 Bsw[128][32];
  const int bid = blockIdx.x;
  const int xcd = bid & 7, slot = bid >> 3;      // slot 0..74
  const int gl = slot / 3, mt = slot - gl * 3;
  const int group = xcd * 25 + gl;
  if (group >= 196) return;
  const int colt = group % 49, t = group / 49;
  const int col0 = colt * 128, o0 = mt * 128;
  const int tid = threadIdx.x, lane = tid & 63, wid = tid >> 6;
  const int wm = wid >> 1, wn = wid & 1;
  const int quad = lane >> 4, nl = lane & 15;
  const __bf16* Ag = wsp + (size_t)9 * WSZ;      // proj = index 3
  const __bf16* Bg = sp + ((size_t)t * NCOLS + col0) * Cn;

  f32x4 acc[4][4] = {};
  bf16x8 aval[6], bval[2];
#pragma unroll
  for (int i = 0; i < 6; ++i) {
    const int u = tid + i * 256, s = u >> 9, rem = u & 511;
    const int row = rem >> 2, kb = rem & 3;
    aval[i] = *(const bf16x8*)(Ag + (size_t)s * WSZ + (size_t)(o0 + row) * Cn + kb * 8);
  }
#pragma unroll
  for (int i = 0; i < 2; ++i) {
    const int u = tid + i * 256, row = u >> 2, kb = u & 3;
    bval[i] = *(const bf16x8*)(Bg + (size_t)row * Cn + kb * 8);
  }

  for (int kk = 0; kk < 12; ++kk) {
    __syncthreads();
#pragma unroll
    for (int i = 0; i < 6; ++i) {
      const int u = tid + i * 256, s = u >> 9, rem = u & 511;
      const int row = rem >> 2, kb = rem & 3;
      const int kbp = kb ^ ((row >> 1) & 3);
      *(bf16x8*)&Asw[s][row][kbp * 8] = aval[i];
    }
#pragma unroll
    for (int i = 0; i < 2; ++i) {
      const int u = tid + i * 256, row = u >> 2, kb = u & 3;
      const int kbp = kb ^ ((row >> 1) & 3);
      *(bf16x8*)&Bsw[row][kbp * 8] = bval[i];
    }
    __syncthreads();
    if (kk < 11) {
      const int k0n = (kk + 1) * 32;
#pragma unroll
      for (int i = 0; i < 6; ++i) {
        const int u = tid + i * 256, s = u >> 9, rem = u & 511;
        const int row = rem >> 2, kb = rem & 3;
        aval[i] = *(const bf16x8*)(Ag + (size_t)s * WSZ +
                                   (size_t)(o0 + row) * Cn + k0n + kb * 8);
      }
#pragma unroll
      for (int i = 0; i < 2; ++i) {
        const int u = tid + i * 256, row = u >> 2, kb = u & 3;
        bval[i] = *(const bf16x8*)(Bg + (size_t)row * Cn + k0n + kb * 8);
      }
    }
    bf16x8 af[3][4], bfr[4];
#pragma unroll
    for (int i = 0; i < 4; ++i) {
      const int ra = wm * 64 + i * 16 + nl;
      const int rb = wn * 64 + i * 16 + nl;
      const int ka = (quad ^ ((ra >> 1) & 3)) * 8;
      const int kb2 = (quad ^ ((rb >> 1) & 3)) * 8;
      bfr[i] = *(const bf16x8*)&Bsw[rb][kb2];
#pragma unroll
      for (int s = 0; s < 3; ++s)
        af[s][i] = *(const bf16x8*)&Asw[s][ra][ka];
    }
#pragma unroll
    for (int mi = 0; mi < 4; ++mi)
#pragma unroll
      for (int ni = 0; ni < 4; ++ni) {
        f32x4 c = acc[mi][ni];
        c = __builtin_amdgcn_mfma_f32_16x16x32_bf16(af[0][mi], bfr[ni], c, 0, 0, 0);
        c = __builtin_amdgcn_mfma_f32_16x16x32_bf16(af[1][mi], bfr[ni], c, 0, 0, 0);
        c = __builtin_amdgcn_mfma_f32_16x16x32_bf16(af[2][mi], bfr[ni], c, 0, 0, 0);
        acc[mi][ni] = c;
      }
  }
#pragma unroll
  for (int mi = 0; mi < 4; ++mi) {
    const int ob = o0 + wm * 64 + mi * 16 + quad * 4;
    const f32x4 sh4 = *(const f32x4*)&shv[3 * Cn + ob];
#pragma unroll
    for (int ni = 0; ni < 4; ++ni) {
      const int col = col0 + wn * 64 + ni * 16 + nl;
      f32x4 o4;
#pragma unroll
      for (int r = 0; r < 4; ++r) o4[r] = acc[mi][ni][r] + sh4[r];
      *(f32x4*)(z + ((size_t)t * NCOLS + col) * Cn + ob) = o4;
    }
  }
}

// ---------------------------------------------------------------------------
// Final LIF(1.0) with layout transpose: z[t][col][o] -> out[t,b,o,n].
// LDS tile per (b, 32-o slab); coalesced reads and writes.
// ---------------------------------------------------------------------------
__global__ __launch_bounds__(256) void lif_out_T(
    const float* __restrict__ z, float* __restrict__ out) {
  __shared__ float tile[Nn][36];   // row stride 144 B (16B-aligned)
  const int ot = blockIdx.x, b = blockIdx.y;
  const int o0 = ot * 32;
  const int tid = threadIdx.x;
  float v[25];
#pragma unroll
  for (int j = 0; j < 25; ++j) v[j] = 0.f;

  for (int t = 0; t < Tn; ++t) {
    for (int u = tid; u < Nn * 8; u += 256) {
      const int row = u >> 3, jj = u & 7;
      *(f32x4*)&tile[row][jj * 4] =
          *(const f32x4*)(z + ((size_t)t * NCOLS + (size_t)b * Nn + row) * Cn + o0 + jj * 4);
    }
    __syncthreads();
#pragma unroll
    for (int j = 0; j < 25; ++j) {
      const int e = tid + j * 256;
      if (e < 32 * Nn) {
        const int o = e / Nn, n = e - o * Nn;
        const float x = tile[n][o];
        const float nv = v[j] + (x - v[j]) * 0.5f;
        const bool s = nv >= 1.0f;
        out[(size_t)t * BCNn + (size_t)b * CNn + (size_t)(o0 + o) * Nn + n] = s ? 1.0f : 0.0f;
        v[j] = s ? 0.f : nv;
      }
    }
    __syncthreads();
  }
}

// ===========================================================================
extern "C" void kernel_launch(void* const* d_in, const int* in_sizes, int n_in,
                              void* d_out, int out_size, void* d_ws, size_t ws_size,
                              hipStream_t stream) {
  const float* x      = (const float*)d_in[0];
  const float* policy = (const float*)d_in[1];
  const float* qw = (const float*)d_in[2];
  const float* qg = (const float*)d_in[3];
  const float* qb_ = (const float*)d_in[4];
  const float* qm = (const float*)d_in[5];
  const float* qv = (const float*)d_in[6];
  const float* kw = (const float*)d_in[7];
  const float* kg = (const float*)d_in[8];
  const float* kbe = (const float*)d_in[9];
  const float* km = (const float*)d_in[10];
  const float* kv = (const float*)d_in[11];
  const float* vw = (const float*)d_in[12];
  const float* vg = (const float*)d_in[13];
  const float* vbe = (const float*)d_in[14];
  const float* vm = (const float*)d_in[15];
  const float* vv = (const float*)d_in[16];
  const float* pw = (const float*)d_in[17];
  const float* pg = (const float*)d_in[18];
  const float* pbe = (const float*)d_in[19];
  const float* pm = (const float*)d_in[20];
  const float* pv = (const float*)d_in[21];
  const float* pbias = (const float*)d_in[22];
  float* out = (float*)d_out;

  // workspace layout (bytes): total ~103.5 MB (harness provides >=161 MB,
  // proven by R3/R4 main paths running)
  char* base = (char*)d_ws;
  float* xT   = (float*)base;                               // 38,535,168
  __bf16* wsp = (__bf16*)(base + (size_t)TBCNn * 4);        //  3,538,944
  float* shv  = (float*)((char*)wsp + (size_t)12 * WSZ * 2);//      6,144
  u32* bq     = (u32*)((char*)shv + 4 * Cn * 4);            //  3,612,672 (x3)
  u32* bk = bq + PBITS;
  u32* bv = bk + PBITS;
  __bf16* sp  = (__bf16*)(bv + PBITS);                      // 19,267,584
  float* z    = (float*)((char*)sp + (size_t)TBCNn * 2);    // 38,535,168

  WSplitArgs wa;
  wa.w[0] = qw; wa.g[0] = qg; wa.be[0] = qb_; wa.mu[0] = qm; wa.va[0] = qv;
  wa.w[1] = kw; wa.g[1] = kg; wa.be[1] = kbe; wa.mu[1] = km; wa.va[1] = kv;
  wa.w[2] = vw; wa.g[2] = vg; wa.be[2] = vbe; wa.mu[2] = vm; wa.va[2] = vv;
  wa.w[3] = pw; wa.g[3] = pg; wa.be[3] = pbe; wa.mu[3] = pm; wa.va[3] = pv;
  wa.bias = pbias;
  split_w<<<2304, 256, 0, stream>>>(wa, wsp, shv);
  transpose_x<<<dim3(4, 32, 2), 256, 0, stream>>>(x, xT);

  BitsOut BO; BO.b[0] = bq; BO.b[1] = bk; BO.b[2] = bv;
  gemm_qkv_pack<<<448, 256, 0, stream>>>(xT, wsp, shv, BO);
  attn_lif<<<Bn * Hn, 256, 0, stream>>>(bq, bk, bv, policy, sp);
  gemm_proj_mfma<<<600, 256, 0, stream>>>(sp, wsp, shv, z);
  lif_out_T<<<dim3(12, 32), 256, 0, stream>>>(z, out);
}